// Round 9
// baseline (196.524 us; speedup 1.0000x reference)
//
#include <hip/hip_runtime.h>
#include <stdint.h>

#define NB 2
#define NS 2048
#define NHID 1024
#define NHEADS 4
#define DHEAD 256
#define NP 128            // DHEAD/2
#define QK_SCALE 0.0625f  // HD^-0.5

typedef unsigned short ushort_t;
typedef __bf16 bf16x8 __attribute__((ext_vector_type(8)));
typedef float floatx4 __attribute__((ext_vector_type(4)));
typedef short shortx8 __attribute__((ext_vector_type(8)));
typedef unsigned short ushortx4 __attribute__((ext_vector_type(4)));
typedef unsigned short ushortx8 __attribute__((ext_vector_type(8)));

__device__ __forceinline__ float bf2f(ushort_t u) {
    unsigned int x = ((unsigned int)u) << 16;
    return __builtin_bit_cast(float, x);
}
__device__ __forceinline__ ushort_t f2bf(float f) {
    unsigned int u = __builtin_bit_cast(unsigned int, f);
    u += 0x7fff + ((u >> 16) & 1);   // RNE
    return (ushort_t)(u >> 16);
}

__device__ __forceinline__ floatx4 mfma16(bf16x8 a, bf16x8 b, floatx4 c) {
    return __builtin_amdgcn_mfma_f32_16x16x32_bf16(a, b, c, 0, 0, 0);
}

__device__ __forceinline__ void gload_lds16(const void* g, void* l) {
    __builtin_amdgcn_global_load_lds(
        (const __attribute__((address_space(1))) void*)g,
        (__attribute__((address_space(3))) void*)l, 16, 0, 0);
}

// shared sync macros (rule #18 hardened: sched_barrier after counted waits,
// compiler fences pinned to raw s_barrier)
#define QWAITV0  do { asm volatile("s_waitcnt vmcnt(0)" ::: "memory"); \
                      __builtin_amdgcn_sched_barrier(0); } while (0)
#define QWAITV6  do { asm volatile("s_waitcnt vmcnt(6)" ::: "memory"); \
                      __builtin_amdgcn_sched_barrier(0); } while (0)
#define QWAITV8  do { asm volatile("s_waitcnt vmcnt(8)" ::: "memory"); \
                      __builtin_amdgcn_sched_barrier(0); } while (0)
#define QWAITL   do { asm volatile("s_waitcnt lgkmcnt(0)" ::: "memory"); \
                      __builtin_amdgcn_sched_barrier(0); } while (0)
#define QBAR     do { asm volatile("" ::: "memory"); \
                      __builtin_amdgcn_s_barrier(); \
                      asm volatile("" ::: "memory"); } while (0)

// ---------------- fused cast fp32 -> bf16 for hidden + Wqkv + Wo ----------------
#define N4_H (4096 * 1024 / 4)
#define N4_WQ (3072 * 1024 / 4)
#define N4_WO (1024 * 1024 / 4)
__global__ __launch_bounds__(256) void cast3_kernel(const float* __restrict__ inH,
                                                    const float* __restrict__ inWq,
                                                    const float* __restrict__ inWo,
                                                    ushort_t* __restrict__ out) {
    int i = blockIdx.x * 256 + threadIdx.x;
    const float* src;
    int j = i;
    if (i < N4_H) {
        src = inH;
    } else if (i < N4_H + N4_WQ) {
        src = inWq; j = i - N4_H;
    } else {
        src = inWo; j = i - (N4_H + N4_WQ);
    }
    float4 v = ((const float4*)src)[j];
    ushortx4 o = { f2bf(v.x), f2bf(v.y), f2bf(v.z), f2bf(v.w) };
    ((ushortx4*)out)[i] = o;
}

// ============ GEMM2 (attn @ Wo^T): 128x64 tile, BK=64, 3-buffer depth-2 ============
// Round 9: 3rd buffer (72 KB, still 2 blk/CU) -> tile kt+2 staged during kt,
// waited at kt+2 with vmcnt(6): ~700 cyc flight instead of ~80 (round-8 was
// depth-1 vmcnt(0) -> ~500 cyc L2 latency exposed per tile).
__global__ __launch_bounds__(256, 2) void gemm_bt_f32s(const ushort_t* __restrict__ A,
                                                       const ushort_t* __restrict__ Bt,
                                                       float* __restrict__ C,
                                                       int M, int N, int K) {
    __shared__ ushort_t sA[3][8192];   // [buf][128 rows x 64 cols]
    __shared__ ushort_t sB[3][4096];   // [buf][64 rows x 64 cols]
    const int t = threadIdx.x;
    const int f = blockIdx.x;            // 0..511
    const int xcd = f & 7;
    const int idx = f >> 3;              // 0..63
    // per XCD: 4 M-panels (fastest) x 16 N-tiles. WS = 4x256KB + 2MB = 3MB -> L2.
    const int m0 = (xcd * 4 + (idx & 3)) * 128;
    const int n0 = (idx >> 2) * 64;
    const int w = t >> 6, l = t & 63;
    const int wr = w >> 1, wc = w & 1;   // 2M x 2N wave grid, wave = 64x32
    const int wrm = wr * 64, wcn = wc * 32;
    const int lc = l & 15, lq = l >> 4;

    floatx4 acc[4][2];
#pragma unroll
    for (int i = 0; i < 4; i++)
#pragma unroll
        for (int j = 0; j < 2; j++) acc[i][j] = (floatx4){0.f, 0.f, 0.f, 0.f};

    // staging: issues of 256 x 16B = 32 rows x 64 cols. thread t -> row t>>3,
    // phys chunk t&7, logical source chunk ((t&7)-(row&7))&7 (rot (c+R)&7).
    const int arow = t >> 3;                                   // 0..31
    const int ac8 = ((((t & 7) - (arow & 7)) & 7)) * 8;
    const ushort_t* Ab = A + (size_t)(m0 + arow) * K + ac8;
    const ushort_t* Bb = Bt + (size_t)(n0 + arow) * K + ac8;
    const int ldst = t * 8;

    auto STAGE = [&](int buf, int kk) {                        // 6 loads / tile
#pragma unroll
        for (int is = 0; is < 4; is++)
            gload_lds16(Ab + (size_t)(is * 32) * K + kk, &sA[buf][is * 2048 + ldst]);
#pragma unroll
        for (int is = 0; is < 2; is++)
            gload_lds16(Bb + (size_t)(is * 32) * K + kk, &sB[buf][is * 2048 + ldst]);
    };
    auto COMPUTE = [&](int buf) {
        const ushort_t* cA = sA[buf];
        const ushort_t* cB = sB[buf];
        bf16x8 af[4][2], bfr[2][2];
#pragma unroll
        for (int ii = 0; ii < 4; ii++) {
            const int R = wrm + ii * 16 + lc;
            af[ii][0] = *(const bf16x8*)&cA[R * 64 + ((lq + R) & 7) * 8];
            af[ii][1] = *(const bf16x8*)&cA[R * 64 + ((4 + lq + R) & 7) * 8];
        }
#pragma unroll
        for (int jj = 0; jj < 2; jj++) {
            const int R = wcn + jj * 16 + lc;
            bfr[jj][0] = *(const bf16x8*)&cB[R * 64 + ((lq + R) & 7) * 8];
            bfr[jj][1] = *(const bf16x8*)&cB[R * 64 + ((4 + lq + R) & 7) * 8];
        }
        QWAITL;
        __builtin_amdgcn_s_setprio(1);
#pragma unroll
        for (int ii = 0; ii < 4; ii++)
#pragma unroll
            for (int jj = 0; jj < 2; jj++) {
                acc[ii][jj] = mfma16(af[ii][0], bfr[jj][0], acc[ii][jj]);
                acc[ii][jj] = mfma16(af[ii][1], bfr[jj][1], acc[ii][jj]);
            }
        __builtin_amdgcn_s_setprio(0);
    };

    STAGE(0, 0); STAGE(1, 64);

#pragma unroll 1
    for (int kt = 0; kt < 15; ++kt) {
        QWAITV6;      // retires tile kt (staged >=2 phases ago); keeps kt+1 in flight
        QBAR;         // cross-wave visibility; also: all reads of buf (kt+2)%3 done
        const int cb = kt % 3;
        if (kt < 14) STAGE((kt + 2) % 3, (kt + 2) * 64);
        COMPUTE(cb);
    }
    QWAITV0;          // tile 15 resident
    QBAR;
    COMPUTE(15 % 3);

#pragma unroll
    for (int i = 0; i < 4; i++) {
        int row = m0 + wrm + i * 16 + lq * 4;
#pragma unroll
        for (int j = 0; j < 2; j++) {
            int col = n0 + wcn + j * 16 + lc;
#pragma unroll
            for (int r = 0; r < 4; r++)
                C[(size_t)(row + r) * N + col] = acc[i][j][r];
        }
    }
}

// ================== QKV GEMM: 256x192 tile, BK=64, 2-buffer, grid=256 ==================
// Round-7 version (passed, 45.5us, 0 conflicts). Unchanged. (Counted-wait analysis:
// every phase reads rows from BOTH staged halves -> P1 requires the whole tile
// resident -> vmcnt(0) is required at 2 buffers; a 3rd buffer doesn't fit LDS.)
__global__ __launch_bounds__(512, 2) void gemm_qkv(const ushort_t* __restrict__ A,
                                                   const ushort_t* __restrict__ Bt,
                                                   const float* __restrict__ fre,
                                                   const float* __restrict__ fim,
                                                   ushort_t* __restrict__ Q,
                                                   ushort_t* __restrict__ Kk,
                                                   ushort_t* __restrict__ Vt) {
    __shared__ ushort_t sA[2][16384];   // [buf][256 rows x 64 cols]
    __shared__ ushort_t sB[2][12288];   // [buf][192 rows x 64 cols]
    const int t = threadIdx.x;
    const int f = blockIdx.x;                  // 0..255
    const int xcd = f & 7;
    const int idx = f >> 3;                    // 0..31
    const int mreg = xcd >> 1, nreg = xcd & 1;
    const int im = idx & 3, in = idx >> 2;     // im 0..3, in 0..7
    const int m0 = (mreg * 4 + im) * 256;
    const int n0 = (nreg * 8 + in) * 192;
    const int w = t >> 6, l = t & 63;
    const int wr = w >> 2, wc = w & 3;         // 2M x 4N wave grid
    const int wrm = wr * 128, wcn = wc * 48;   // per-wave 128 x 48
    const int lc = l & 15, lq = l >> 4;

    floatx4 acc[8][3];
#pragma unroll
    for (int i = 0; i < 8; i++)
#pragma unroll
        for (int j = 0; j < 3; j++) acc[i][j] = (floatx4){0.f, 0.f, 0.f, 0.f};

    const int arow = t >> 3;                                   // 0..63
    const int ac8 = ((((t & 7) - (arow & 7)) & 7)) * 8;
    const ushort_t* Ab = A + (size_t)(m0 + arow) * 1024 + ac8;
    const ushort_t* Bb = Bt + (size_t)(n0 + arow) * 1024 + ac8;
    const int ldst = t * 8;

    auto STAGE_A2 = [&](int buf, int half, int kk) {           // rows half*128..+127
        gload_lds16(Ab + (size_t)(half * 128) * 1024 + kk, &sA[buf][half * 8192 + ldst]);
        gload_lds16(Ab + (size_t)(half * 128 + 64) * 1024 + kk, &sA[buf][half * 8192 + 4096 + ldst]);
    };
    auto STAGE_B3 = [&](int buf, int kk) {                     // all 192 rows
        gload_lds16(Bb + kk, &sB[buf][ldst]);
        gload_lds16(Bb + (size_t)64 * 1024 + kk, &sB[buf][4096 + ldst]);
        gload_lds16(Bb + (size_t)128 * 1024 + kk, &sB[buf][8192 + ldst]);
    };

    // prologue: tile 0 into buf 0
    STAGE_A2(0, 0, 0); STAGE_A2(0, 1, 0); STAGE_B3(0, 0);

#pragma unroll 1
    for (int kt = 0; kt < 16; ++kt) {
        const int b = kt & 1, nb = b ^ 1;
        const int kn = (kt + 1) * 64;
        const ushort_t* cA = sA[b];
        const ushort_t* cB = sB[b];
        bf16x8 af[4][2], bfr[3][2];

        // ---- P1: A-mh0 + B j0,j1 ----
        QWAITV0;
        QBAR;
#pragma unroll
        for (int ii = 0; ii < 4; ii++) {
            const int R = wrm + ii * 16 + lc;
            af[ii][0] = *(const bf16x8*)&cA[R * 64 + ((lq + R) & 7) * 8];
            af[ii][1] = *(const bf16x8*)&cA[R * 64 + ((4 + lq + R) & 7) * 8];
        }
#pragma unroll
        for (int jj = 0; jj < 2; jj++) {
            const int R = wcn + jj * 16 + lc;
            bfr[jj][0] = *(const bf16x8*)&cB[R * 64 + ((lq + R) & 7) * 8];
            bfr[jj][1] = *(const bf16x8*)&cB[R * 64 + ((4 + lq + R) & 7) * 8];
        }
        if (kt < 15) STAGE_A2(nb, 0, kn);
        QWAITL;
        __builtin_amdgcn_s_setprio(1);
#pragma unroll
        for (int ii = 0; ii < 4; ii++)
#pragma unroll
            for (int jj = 0; jj < 2; jj++) {
                acc[ii][jj] = mfma16(af[ii][0], bfr[jj][0], acc[ii][jj]);
                acc[ii][jj] = mfma16(af[ii][1], bfr[jj][1], acc[ii][jj]);
            }
        __builtin_amdgcn_s_setprio(0);

        // ---- P2: B j2 (mh0) ----
        QBAR;
        {
            const int R = wcn + 32 + lc;
            bfr[2][0] = *(const bf16x8*)&cB[R * 64 + ((lq + R) & 7) * 8];
            bfr[2][1] = *(const bf16x8*)&cB[R * 64 + ((4 + lq + R) & 7) * 8];
        }
        if (kt < 15) STAGE_A2(nb, 1, kn);
        QWAITL;
        __builtin_amdgcn_s_setprio(1);
#pragma unroll
        for (int ii = 0; ii < 4; ii++) {
            acc[ii][2] = mfma16(af[ii][0], bfr[2][0], acc[ii][2]);
            acc[ii][2] = mfma16(af[ii][1], bfr[2][1], acc[ii][2]);
        }
        __builtin_amdgcn_s_setprio(0);

        // ---- P3: A-mh1 (bfr[2] still live) ----
        QBAR;
#pragma unroll
        for (int ii = 0; ii < 4; ii++) {
            const int R = wrm + 64 + ii * 16 + lc;
            af[ii][0] = *(const bf16x8*)&cA[R * 64 + ((lq + R) & 7) * 8];
            af[ii][1] = *(const bf16x8*)&cA[R * 64 + ((4 + lq + R) & 7) * 8];
        }
        if (kt < 15) STAGE_B3(nb, kn);
        QWAITL;
        __builtin_amdgcn_s_setprio(1);
#pragma unroll
        for (int ii = 0; ii < 4; ii++) {
            acc[4 + ii][2] = mfma16(af[ii][0], bfr[2][0], acc[4 + ii][2]);
            acc[4 + ii][2] = mfma16(af[ii][1], bfr[2][1], acc[4 + ii][2]);
        }
        __builtin_amdgcn_s_setprio(0);

        // ---- P4: B j0,j1 (mh1) ----
        QBAR;
#pragma unroll
        for (int jj = 0; jj < 2; jj++) {
            const int R = wcn + jj * 16 + lc;
            bfr[jj][0] = *(const bf16x8*)&cB[R * 64 + ((lq + R) & 7) * 8];
            bfr[jj][1] = *(const bf16x8*)&cB[R * 64 + ((4 + lq + R) & 7) * 8];
        }
        QWAITL;
        __builtin_amdgcn_s_setprio(1);
#pragma unroll
        for (int ii = 0; ii < 4; ii++)
#pragma unroll
            for (int jj = 0; jj < 2; jj++) {
                acc[4 + ii][jj] = mfma16(af[ii][0], bfr[jj][0], acc[4 + ii][jj]);
                acc[4 + ii][jj] = mfma16(af[ii][1], bfr[jj][1], acc[4 + ii][jj]);
            }
        __builtin_amdgcn_s_setprio(0);
    }

    // ---- fused epilogue (RoPE on Q/K, transpose-store V) ----
#pragma unroll
    for (int i = 0; i < 8; i++) {
        int row = m0 + wrm + i * 16 + lq * 4;     // + r
        int bb = row >> 11;                       // uniform per block
        int srow2 = row & 2047;
#pragma unroll
        for (int j = 0; j < 3; j++) {
            int c0 = n0 + wcn + j * 16;           // 16-aligned, lane-uniform
            int sect = c0 >> 10;
            int h = (c0 >> 8) & 3;
            int d = (c0 & 255) + lc;
            int bh = bb * NHEADS + h;
            if (sect == 2) {
                ushortx4 pack = { f2bf(acc[i][j][0]), f2bf(acc[i][j][1]),
                                  f2bf(acc[i][j][2]), f2bf(acc[i][j][3]) };
                *(ushortx4*)&Vt[((size_t)bh * 256 + d) * NS + srow2] = pack;
            } else {
                int p = d >> 1;
                int odd = d & 1;
                ushort_t* dst = (sect == 0) ? Q : Kk;
#pragma unroll
                for (int r = 0; r < 4; r++) {
                    float v = acc[i][j][r];
                    float vp = __shfl_xor(v, 1);
                    int s = srow2 + r;
                    float c = fre[s * NP + p], si = fim[s * NP + p];
                    float out = odd ? (vp * si + v * c) : (v * c - vp * si);
                    if (sect == 0) out *= QK_SCALE;
                    dst[((size_t)bh * NS + s) * DHEAD + d] = f2bf(out);
                }
            }
        }
    }
}

// ---------------- flash attention v5: cross-chunk K prefetch (round 9) ----------------
// K(c+1) staged right after QK^T(c)'s barrier (sK reusable there) and waited at
// the TOP of chunk c+1 -> K latency hides under a whole PV+exp phase. V staged
// at chunk top, waited after QK^T (unchanged). vmcnt never drains to 0 in the
// loop except the final chunk. LDS unchanged (73 KB, 2 blocks/CU).
#define BQ3 128
#define BKV3 64
#define PPAD 72
#define CHCAP 6
#define NPART_BH 51
#define OPART_SPLIT 224   // partials 0..223 in region A, rest in region B

__global__ __launch_bounds__(256, 2) void flash_attn4(const ushort_t* __restrict__ Q,
                                                      const ushort_t* __restrict__ K,
                                                      const ushort_t* __restrict__ Vt,
                                                      ushort_t* __restrict__ OpA,
                                                      ushort_t* __restrict__ OpB,
                                                      float* __restrict__ ml) {
    __shared__ ushort_t sK[BKV3 * 256];        // 32768 B, [key][d] rot-swizzled
    __shared__ ushort_t sV[DHEAD * 64];        // 32768 B, [d][key] rot-swizzled
    __shared__ ushort_t sP[4][16 * PPAD];      // 9216 B, per-wave, gq-sequential

    int rem = blockIdx.x, qt = 15, nsp;
    for (;;) {
        nsp = (2 * (qt + 1) + CHCAP - 1) / CHCAP;
        if (rem < nsp) break;
        rem -= nsp;
        qt--;
    }
    const int nch = 2 * (qt + 1);
    const int cbeg = rem * CHCAP;
    const int cend = (cbeg + CHCAP < nch) ? cbeg + CHCAP : nch;

    const int h = blockIdx.y, b = blockIdx.z;
    const int t = threadIdx.x, w = t >> 6, l = t & 63;
    const int lc = l & 15, lq = l >> 4;
    const int bh = b * NHEADS + h;
    const size_t base = (size_t)bh * NS * DHEAD;
    const int q0 = qt * BQ3;

    // per-lane invariant staging offsets (rotation amount is j-invariant)
    const int krb = w * 2 + (l >> 5);                          // K row base (+8 per issue)
    const int kck = ((l & 31) - (krb & 7)) & 31;               // logical chunk
    const size_t koff = (size_t)krb * 256 + kck * 8;           // + (kb + j*8)*256
    const int vrb = w * 8 + (l >> 3);                          // V row base (+32 per issue)
    const int vck = ((l & 7) - (vrb & 7)) & 7;
    const size_t voff = (size_t)vrb * NS + vck * 8;            // + kb + j*32*NS
    ushort_t* dK = &sK[w * 512 + l * 8];                       // + j*2048
    ushort_t* dV = &sV[w * 512 + l * 8];

    // Q fragments: wave w owns rows [q0+w*32, +32), two 16-row groups
    bf16x8 qf[2][8];
#pragma unroll
    for (int gq = 0; gq < 2; gq++) {
        const ushort_t* qrow = Q + base + (size_t)(q0 + w * 32 + gq * 16 + lc) * DHEAD + lq * 8;
#pragma unroll
        for (int dk = 0; dk < 8; dk++) qf[gq][dk] = *(const bf16x8*)(qrow + dk * 32);
    }
    QWAITV0;   // drain qf loads so the DMA vmcnt ledger below is exact

    // prologue: K(cbeg) in flight
    {
        const ushort_t* ksrc0 = K + base + (size_t)(cbeg * BKV3) * 256 + koff;
#pragma unroll
        for (int j = 0; j < 8; j++)
            gload_lds16(ksrc0 + j * (8 * 256), dK + j * 2048);
    }

    floatx4 accO[2][16];
#pragma unroll
    for (int gq = 0; gq < 2; gq++)
#pragma unroll
        for (int j = 0; j < 16; j++) accO[gq][j] = (floatx4){0.f, 0.f, 0.f, 0.f};
    float lrun[2][4] = {{0.f, 0.f, 0.f, 0.f}, {0.f, 0.f, 0.f, 0.f}};

    for (int kc = cbeg; kc < cend; kc++) {
        const int kb = kc * BKV3;

        QBAR;   // all waves' PV(prev) reads of sV done -> sV reusable
        {       // stage V(kc); waited after QK^T
            const ushort_t* vsrc = Vt + base + kb + voff;
#pragma unroll
            for (int j = 0; j < 8; j++)
                gload_lds16(vsrc + j * (32 * NS), dV + j * 2048);
        }
        QWAITV8;   // retires K(kc) (staged a whole chunk ago); V(kc) in flight
        QBAR;      // K visible to all waves

        // S = Q K^T : 8 independent chains; K-frag shared by both q-groups
        floatx4 sfr[2][4];
#pragma unroll
        for (int gq = 0; gq < 2; gq++)
#pragma unroll
            for (int g = 0; g < 4; g++) sfr[gq][g] = (floatx4){0.f, 0.f, 0.f, 0.f};
#pragma unroll
        for (int dk = 0; dk < 8; dk++) {
#pragma unroll
            for (int g = 0; g < 4; g++) {
                int R = g * 16 + lc;
                int phys = (dk * 4 + lq + (R & 7)) & 31;
                bf16x8 bk = *(const bf16x8*)&sK[R * 256 + phys * 8];
                sfr[0][g] = mfma16(qf[0][dk], bk, sfr[0][g]);
                sfr[1][g] = mfma16(qf[1][dk], bk, sfr[1][g]);
            }
        }

        // causal mask only on the two diagonal chunks
        if (kc >= nch - 2) {
#pragma unroll
            for (int gq = 0; gq < 2; gq++)
#pragma unroll
                for (int g = 0; g < 4; g++) {
                    int kg = kb + g * 16 + lc;
                    int qr = q0 + w * 32 + gq * 16 + lq * 4;
#pragma unroll
                    for (int r = 0; r < 4; r++)
                        if (kg > qr + r) sfr[gq][g][r] = -1e30f;
                }
        }

        QBAR;   // all waves' QK reads of sK done -> sK reusable
        if (kc + 1 < cend) {
            const ushort_t* ksrc = K + base + (size_t)((kc + 1) * BKV3) * 256 + koff;
#pragma unroll
            for (int j = 0; j < 8; j++)
                gload_lds16(ksrc + j * (8 * 256), dK + j * 2048);
            QWAITV8;   // retires V(kc); K(kc+1) stays in flight across PV
        } else {
            QWAITV0;   // final chunk: only V(kc) outstanding
        }
        QBAR;          // V visible to all waves

        // gq-sequential: exp -> P(LDS) -> A-frag -> PV
        ushort_t* pw = sP[w];
#pragma unroll
        for (int gq = 0; gq < 2; gq++) {
#pragma unroll
            for (int g = 0; g < 4; g++)
#pragma unroll
                for (int r = 0; r < 4; r++) {
                    float p = __expf(sfr[gq][g][r]);
                    lrun[gq][r] += p;
                    pw[(lq * 4 + r) * PPAD + g * 16 + lc] = f2bf(p);
                }
            bf16x8 ap0 = *(const bf16x8*)&pw[lc * PPAD + lq * 8];
            bf16x8 ap1 = *(const bf16x8*)&pw[lc * PPAD + 32 + lq * 8];
#pragma unroll
            for (int j = 0; j < 16; j++) {
                int D = j * 16 + lc;
                int ph0 = (lq + (D & 7)) & 7;
                int ph1 = (4 + lq + (D & 7)) & 7;
                bf16x8 bv0 = *(const bf16x8*)&sV[D * 64 + ph0 * 8];
                bf16x8 bv1 = *(const bf16x8*)&sV[D * 64 + ph1 * 8];
                accO[gq][j] = mfma16(ap0, bv0, accO[gq][j]);
                accO[gq][j] = mfma16(ap1, bv1, accO[gq][j]);
            }
        }
    }

    // ---- epilogue: unnormalized partial O (bf16) + row sums l ----
    const int pid = bh * NPART_BH + blockIdx.x;
    ushort_t* op = (pid < OPART_SPLIT) ? OpA + (size_t)pid * (128 * 256)
                                       : OpB + (size_t)(pid - OPART_SPLIT) * (128 * 256);
#pragma unroll
    for (int gq = 0; gq < 2; gq++) {
#pragma unroll
        for (int r = 0; r < 4; r++) {
            int row = w * 32 + gq * 16 + lq * 4 + r;
#pragma unroll
            for (int j = 0; j < 16; j++)
                op[row * 256 + j * 16 + lc] = f2bf(accO[gq][j][r]);
            float lv = lrun[gq][r];
#pragma unroll
            for (int off = 1; off < 16; off <<= 1) lv += __shfl_xor(lv, off);
            if (lc == 0) ml[(size_t)pid * 128 + row] = lv;
        }
    }
}

// ---------------- combine partials: fully parallel, vectorized ----------------
__global__ __launch_bounds__(256) void combine_parts2(const ushort_t* __restrict__ OpA,
                                                      const ushort_t* __restrict__ OpB,
                                                      const float* __restrict__ ml,
                                                      ushort_t* __restrict__ O) {
    const int qt = blockIdx.x >> 3, rsub = blockIdx.x & 7;
    const int h = blockIdx.y, b = blockIdx.z;
    const int bh = b * NHEADS + h;
    int bbase = 0;
    for (int q = 15; q > qt; q--) bbase += (2 * (q + 1) + CHCAP - 1) / CHCAP;
    const int nsp = (2 * (qt + 1) + CHCAP - 1) / CHCAP;
    const int pid0 = bh * NPART_BH + bbase;

    const int t = threadIdx.x;
    const int rl = t >> 4;               // 0..15 local row
    const int c0 = (t & 15) * 16;        // col base
    const int row = rsub * 16 + rl;      // row within 128-row q-tile

    float so[16];
#pragma unroll
    for (int k = 0; k < 16; k++) so[k] = 0.f;
    float sl = 0.f;

    for (int i = 0; i < nsp; i++) {
        int pid = pid0 + i;
        const ushort_t* op = (pid < OPART_SPLIT)
                                 ? OpA + (size_t)pid * (128 * 256)
                                 : OpB + (size_t)(pid - OPART_SPLIT) * (128 * 256);
        const ushort_t* p = op + row * 256 + c0;
        ushortx8 a0 = *(const ushortx8*)p;
        ushortx8 a1 = *(const ushortx8*)(p + 8);
#pragma unroll
        for (int k = 0; k < 8; k++) {
            so[k] += bf2f(a0[k]);
            so[8 + k] += bf2f(a1[k]);
        }
        sl += ml[(size_t)pid * 128 + row];
    }

    float inv = 1.f / sl;
    ushortx8 o0, o1;
#pragma unroll
    for (int k = 0; k < 8; k++) {
        o0[k] = f2bf(so[k] * inv);
        o1[k] = f2bf(so[8 + k] * inv);
    }
    int s = qt * BQ3 + row;
    ushort_t* dst = O + ((size_t)(b * NS + s) * NHEADS + h) * DHEAD + c0;
    *(ushortx8*)dst = o0;
    *(ushortx8*)(dst + 8) = o1;
}

// ---------------- launch ----------------
extern "C" void kernel_launch(void* const* d_in, const int* in_sizes, int n_in,
                              void* d_out, int out_size, void* d_ws, size_t ws_size,
                              hipStream_t stream) {
    const float* hidden = (const float*)d_in[0];
    const float* fre = (const float*)d_in[1];
    const float* fim = (const float*)d_in[2];
    // d_in[3] = mask (causal, reproduced analytically)
    const float* Wqkv = (const float*)d_in[4];
    const float* Wo = (const float*)d_in[5];

    char* ws = (char*)d_ws;
    ushort_t* hb    = (ushort_t*)(ws);                 // [0,8M)   dead after gemm_qkv
    ushort_t* wqkvb = (ushort_t*)(ws + 8388608);       // [8,14M)  dead after gemm_qkv
    ushort_t* wob   = (ushort_t*)(ws + 14680064);      // [14,16M) live till gemm2
    ushort_t* qb    = (ushort_t*)(ws + 16777216);      // [16,24M) dead after flash
    ushort_t* kb    = (ushort_t*)(ws + 25165824);      // [24,32M) dead after flash
    ushort_t* vtb   = (ushort_t*)(ws + 33554432);      // [32,40M) dead after flash
    ushort_t* OpA   = (ushort_t*)(ws);                 // [0,14M)  224 partials (over hb+wqkvb)
    ushort_t* OpB   = (ushort_t*)(ws + 41943040);      // [40M,+11.5M) 184 partials, dead after combine
    ushort_t* oattn = (ushort_t*)(ws + 16777216);      // over dead qb, live till gemm2
    float*    ml    = (float*)(ws + 58720256);         // [56M, +209K)

    cast3_kernel<<<(N4_H + N4_WQ + N4_WO) / 256, 256, 0, stream>>>(hidden, Wqkv, Wo, hb);

    gemm_qkv<<<dim3(256), 512, 0, stream>>>(
        hb, wqkvb, fre, fim, qb, kb, vtb);

    flash_attn4<<<dim3(NPART_BH, NHEADS, NB), 256, 0, stream>>>(qb, kb, vtb, OpA, OpB, ml);
    combine_parts2<<<dim3(128, NHEADS, NB), 256, 0, stream>>>(OpA, OpB, ml, oattn);

    gemm_bt_f32s<<<dim3(512), 256, 0, stream>>>(
        oattn, wob, (float*)d_out, 4096, 1024, 1024);
}

// Round 10
// 181.458 us; speedup vs baseline: 1.0830x; 1.0830x over previous
//
#include <hip/hip_runtime.h>
#include <stdint.h>

#define NB 2
#define NS 2048
#define NHID 1024
#define NHEADS 4
#define DHEAD 256
#define NP 128            // DHEAD/2
#define QK_SCALE 0.0625f  // HD^-0.5

typedef unsigned short ushort_t;
typedef __bf16 bf16x8 __attribute__((ext_vector_type(8)));
typedef float floatx4 __attribute__((ext_vector_type(4)));
typedef short shortx8 __attribute__((ext_vector_type(8)));
typedef unsigned short ushortx4 __attribute__((ext_vector_type(4)));
typedef unsigned short ushortx8 __attribute__((ext_vector_type(8)));

__device__ __forceinline__ float bf2f(ushort_t u) {
    unsigned int x = ((unsigned int)u) << 16;
    return __builtin_bit_cast(float, x);
}
__device__ __forceinline__ ushort_t f2bf(float f) {
    unsigned int u = __builtin_bit_cast(unsigned int, f);
    u += 0x7fff + ((u >> 16) & 1);   // RNE
    return (ushort_t)(u >> 16);
}

__device__ __forceinline__ floatx4 mfma16(bf16x8 a, bf16x8 b, floatx4 c) {
    return __builtin_amdgcn_mfma_f32_16x16x32_bf16(a, b, c, 0, 0, 0);
}

__device__ __forceinline__ void gload_lds16(const void* g, void* l) {
    __builtin_amdgcn_global_load_lds(
        (const __attribute__((address_space(1))) void*)g,
        (__attribute__((address_space(3))) void*)l, 16, 0, 0);
}

// shared sync macros (rule #18 hardened: sched_barrier after counted waits,
// compiler fences pinned to raw s_barrier)
#define QWAITV0  do { asm volatile("s_waitcnt vmcnt(0)" ::: "memory"); \
                      __builtin_amdgcn_sched_barrier(0); } while (0)
#define QWAITV8  do { asm volatile("s_waitcnt vmcnt(8)" ::: "memory"); \
                      __builtin_amdgcn_sched_barrier(0); } while (0)
#define QWAITL   do { asm volatile("s_waitcnt lgkmcnt(0)" ::: "memory"); \
                      __builtin_amdgcn_sched_barrier(0); } while (0)
#define QBAR     do { asm volatile("" ::: "memory"); \
                      __builtin_amdgcn_s_barrier(); \
                      asm volatile("" ::: "memory"); } while (0)

// ---------------- fused cast fp32 -> bf16 for hidden + Wqkv + Wo ----------------
#define N4_H (4096 * 1024 / 4)
#define N4_WQ (3072 * 1024 / 4)
#define N4_WO (1024 * 1024 / 4)
__global__ __launch_bounds__(256) void cast3_kernel(const float* __restrict__ inH,
                                                    const float* __restrict__ inWq,
                                                    const float* __restrict__ inWo,
                                                    ushort_t* __restrict__ out) {
    int i = blockIdx.x * 256 + threadIdx.x;
    const float* src;
    int j = i;
    if (i < N4_H) {
        src = inH;
    } else if (i < N4_H + N4_WQ) {
        src = inWq; j = i - N4_H;
    } else {
        src = inWo; j = i - (N4_H + N4_WQ);
    }
    float4 v = ((const float4*)src)[j];
    ushortx4 o = { f2bf(v.x), f2bf(v.y), f2bf(v.z), f2bf(v.w) };
    ((ushortx4*)out)[i] = o;
}

// ============ GEMM2 (attn @ Wo^T): 128x64 tile, BK=64, 2 blk/CU, direct f32 out ============
// Round-8 version (part of the best passing 191.0us config). Reverted to exactly
// this after round-9's unattributable regression.
__global__ __launch_bounds__(256, 2) void gemm_bt_f32s(const ushort_t* __restrict__ A,
                                                       const ushort_t* __restrict__ Bt,
                                                       float* __restrict__ C,
                                                       int M, int N, int K) {
    __shared__ ushort_t sA[2][8192];   // [buf][128 rows x 64 cols]
    __shared__ ushort_t sB[2][4096];   // [buf][64 rows x 64 cols]
    const int t = threadIdx.x;
    const int f = blockIdx.x;            // 0..511
    const int xcd = f & 7;
    const int idx = f >> 3;              // 0..63
    const int m0 = (xcd * 4 + (idx & 3)) * 128;
    const int n0 = (idx >> 2) * 64;
    const int w = t >> 6, l = t & 63;
    const int wr = w >> 1, wc = w & 1;   // 2M x 2N wave grid, wave = 64x32
    const int wrm = wr * 64, wcn = wc * 32;
    const int lc = l & 15, lq = l >> 4;

    floatx4 acc[4][2];
#pragma unroll
    for (int i = 0; i < 4; i++)
#pragma unroll
        for (int j = 0; j < 2; j++) acc[i][j] = (floatx4){0.f, 0.f, 0.f, 0.f};

    const int arow = t >> 3;                                   // 0..31
    const int ac8 = ((((t & 7) - (arow & 7)) & 7)) * 8;
    const ushort_t* Ab = A + (size_t)(m0 + arow) * K + ac8;
    const ushort_t* Bb = Bt + (size_t)(n0 + arow) * K + ac8;
    const int ldst = t * 8;

    auto STAGE_A = [&](int buf, int kk) {                      // 128 rows, 4 issues
#pragma unroll
        for (int is = 0; is < 4; is++)
            gload_lds16(Ab + (size_t)(is * 32) * K + kk, &sA[buf][is * 2048 + ldst]);
    };
    auto STAGE_B = [&](int buf, int kk) {                      // 64 rows, 2 issues
#pragma unroll
        for (int is = 0; is < 2; is++)
            gload_lds16(Bb + (size_t)(is * 32) * K + kk, &sB[buf][is * 2048 + ldst]);
    };

    STAGE_A(0, 0); STAGE_B(0, 0);

#pragma unroll 1
    for (int kt = 0; kt < 16; ++kt) {
        const int b = kt & 1, nb = b ^ 1;
        const int kn = (kt + 1) * 64;
        const ushort_t* cA = sA[b];
        const ushort_t* cB = sB[b];
        bf16x8 af[4][2], bfr[2][2];

        QWAITV0;     // tile kt's 6 loads (issued during kt-1's MFMA) resident
        QBAR;        // cross-wave visibility; also: all waves done reading buf nb
#pragma unroll
        for (int ii = 0; ii < 4; ii++) {
            const int R = wrm + ii * 16 + lc;
            af[ii][0] = *(const bf16x8*)&cA[R * 64 + ((lq + R) & 7) * 8];
            af[ii][1] = *(const bf16x8*)&cA[R * 64 + ((4 + lq + R) & 7) * 8];
        }
#pragma unroll
        for (int jj = 0; jj < 2; jj++) {
            const int R = wcn + jj * 16 + lc;
            bfr[jj][0] = *(const bf16x8*)&cB[R * 64 + ((lq + R) & 7) * 8];
            bfr[jj][1] = *(const bf16x8*)&cB[R * 64 + ((4 + lq + R) & 7) * 8];
        }
        if (kt < 15) { STAGE_A(nb, kn); STAGE_B(nb, kn); }
        QWAITL;
        __builtin_amdgcn_s_setprio(1);
#pragma unroll
        for (int ii = 0; ii < 4; ii++)
#pragma unroll
            for (int jj = 0; jj < 2; jj++) {
                acc[ii][jj] = mfma16(af[ii][0], bfr[jj][0], acc[ii][jj]);
                acc[ii][jj] = mfma16(af[ii][1], bfr[jj][1], acc[ii][jj]);
            }
        __builtin_amdgcn_s_setprio(0);
    }

#pragma unroll
    for (int i = 0; i < 4; i++) {
        int row = m0 + wrm + i * 16 + lq * 4;
#pragma unroll
        for (int j = 0; j < 2; j++) {
            int col = n0 + wcn + j * 16 + lc;
#pragma unroll
            for (int r = 0; r < 4; r++)
                C[(size_t)(row + r) * N + col] = acc[i][j][r];
        }
    }
}

// ============== QKV GEMM round 10: 128x192 tile, BK=64, 80KB LDS -> 2 blocks/CU ==============
// Theory: the 256x192 version (112KB LDS) ran 1 block/CU = 2 waves/SIMD, so every
// vmcnt(0)+barrier stalled the whole CU (no co-resident block to overlap — m114
// mechanism absent). Same depth-1 schedule at 2 blocks/CU is what makes gemm_bt
// work. Tile 128x192, 8 waves of 64x48, grid 512 = 2/CU. Proven components only:
// BK=64 8-chunk rot swizzle (0 conflicts), stage-inactive-buffer-only (r5 lesson),
// single vmcnt(0)+barrier per K-tile (r8 gemm_bt skeleton).
__global__ __launch_bounds__(512, 4) void gemm_qkv(const ushort_t* __restrict__ A,
                                                   const ushort_t* __restrict__ Bt,
                                                   const float* __restrict__ fre,
                                                   const float* __restrict__ fim,
                                                   ushort_t* __restrict__ Q,
                                                   ushort_t* __restrict__ Kk,
                                                   ushort_t* __restrict__ Vt) {
    __shared__ ushort_t sA[2][8192];    // [buf][128 rows x 64 cols] 16KB
    __shared__ ushort_t sB[2][12288];   // [buf][192 rows x 64 cols] 24KB  (total 80KB)
    const int t = threadIdx.x;
    const int f = blockIdx.x;                  // 0..511
    const int xcd = f & 7;
    const int idx = f >> 3;                    // 0..63
    // XCD regions: 4M x 2N of (8 M-tiles x 8 N-tiles); im fastest (B-panel reuse).
    // Per-XCD WS: 8 A-panels (2MB) + 8 B-panels (3MB) = 5MB.
    const int mreg = xcd & 3, nreg = xcd >> 2;
    const int im = idx & 7, in = idx >> 3;     // im 0..7, in 0..7
    const int m0 = (mreg * 8 + im) * 128;
    const int n0 = (nreg * 8 + in) * 192;
    const int w = t >> 6, l = t & 63;
    const int wr = w >> 2, wc = w & 3;         // 2M x 4N wave grid
    const int wrm = wr * 64, wcn = wc * 48;    // per-wave 64 x 48
    const int lc = l & 15, lq = l >> 4;

    floatx4 acc[4][3];
#pragma unroll
    for (int i = 0; i < 4; i++)
#pragma unroll
        for (int j = 0; j < 3; j++) acc[i][j] = (floatx4){0.f, 0.f, 0.f, 0.f};

    // staging: issues of 512 x 16B = 64 rows x 64 cols. thread t -> row t>>3,
    // phys chunk t&7, logical source chunk ((t&7)-(row&7))&7 (rot (c+R)&7).
    const int arow = t >> 3;                                   // 0..63
    const int ac8 = ((((t & 7) - (arow & 7)) & 7)) * 8;
    const ushort_t* Ab = A + (size_t)(m0 + arow) * 1024 + ac8;
    const ushort_t* Bb = Bt + (size_t)(n0 + arow) * 1024 + ac8;
    const int ldst = t * 8;

    auto STAGE = [&](int buf, int kk) {        // A 2 issues + B 3 issues = 5 loads
        gload_lds16(Ab + kk, &sA[buf][ldst]);
        gload_lds16(Ab + (size_t)64 * 1024 + kk, &sA[buf][4096 + ldst]);
        gload_lds16(Bb + kk, &sB[buf][ldst]);
        gload_lds16(Bb + (size_t)64 * 1024 + kk, &sB[buf][4096 + ldst]);
        gload_lds16(Bb + (size_t)128 * 1024 + kk, &sB[buf][8192 + ldst]);
    };

    STAGE(0, 0);

#pragma unroll 1
    for (int kt = 0; kt < 16; ++kt) {
        const int b = kt & 1, nb = b ^ 1;
        const int kn = (kt + 1) * 64;
        const ushort_t* cA = sA[b];
        const ushort_t* cB = sB[b];
        bf16x8 af[4][2], bfr[3][2];

        QWAITV0;     // tile kt's 5 loads resident
        QBAR;        // cross-wave visibility; all waves done reading buf nb
#pragma unroll
        for (int ii = 0; ii < 4; ii++) {
            const int R = wrm + ii * 16 + lc;
            af[ii][0] = *(const bf16x8*)&cA[R * 64 + ((lq + R) & 7) * 8];
            af[ii][1] = *(const bf16x8*)&cA[R * 64 + ((4 + lq + R) & 7) * 8];
        }
#pragma unroll
        for (int jj = 0; jj < 3; jj++) {
            const int R = wcn + jj * 16 + lc;
            bfr[jj][0] = *(const bf16x8*)&cB[R * 64 + ((lq + R) & 7) * 8];
            bfr[jj][1] = *(const bf16x8*)&cB[R * 64 + ((4 + lq + R) & 7) * 8];
        }
        if (kt < 15) STAGE(nb, kn);
        QWAITL;
        __builtin_amdgcn_s_setprio(1);
#pragma unroll
        for (int ii = 0; ii < 4; ii++)
#pragma unroll
            for (int jj = 0; jj < 3; jj++) {
                acc[ii][jj] = mfma16(af[ii][0], bfr[jj][0], acc[ii][jj]);
                acc[ii][jj] = mfma16(af[ii][1], bfr[jj][1], acc[ii][jj]);
            }
        __builtin_amdgcn_s_setprio(0);
    }

    // ---- fused epilogue (RoPE on Q/K, transpose-store V) ----
    // sect/head per 16-col fragment (192-wide tiles straddle 1024-boundaries).
#pragma unroll
    for (int i = 0; i < 4; i++) {
        int row = m0 + wrm + i * 16 + lq * 4;     // + r
        int bb = row >> 11;                       // uniform per block
        int srow2 = row & 2047;
#pragma unroll
        for (int j = 0; j < 3; j++) {
            int c0 = n0 + wcn + j * 16;           // 16-aligned, lane-uniform
            int sect = c0 >> 10;
            int h = (c0 >> 8) & 3;
            int d = (c0 & 255) + lc;
            int bh = bb * NHEADS + h;
            if (sect == 2) {
                ushortx4 pack = { f2bf(acc[i][j][0]), f2bf(acc[i][j][1]),
                                  f2bf(acc[i][j][2]), f2bf(acc[i][j][3]) };
                *(ushortx4*)&Vt[((size_t)bh * 256 + d) * NS + srow2] = pack;
            } else {
                int p = d >> 1;
                int odd = d & 1;
                ushort_t* dst = (sect == 0) ? Q : Kk;
#pragma unroll
                for (int r = 0; r < 4; r++) {
                    float v = acc[i][j][r];
                    float vp = __shfl_xor(v, 1);
                    int s = srow2 + r;
                    float c = fre[s * NP + p], si = fim[s * NP + p];
                    float out = odd ? (vp * si + v * c) : (v * c - vp * si);
                    if (sect == 0) out *= QK_SCALE;
                    dst[((size_t)bh * NS + s) * DHEAD + d] = f2bf(out);
                }
            }
        }
    }
}

// ---------------- flash attention v4 + split K/V waits (round-8 version) ----------------
// Reverted to exactly the round-8 kernel (part of the 191.0us config).
#define BQ3 128
#define BKV3 64
#define PPAD 72
#define CHCAP 6
#define NPART_BH 51
#define OPART_SPLIT 224   // partials 0..223 in region A, rest in region B

__global__ __launch_bounds__(256, 2) void flash_attn4(const ushort_t* __restrict__ Q,
                                                      const ushort_t* __restrict__ K,
                                                      const ushort_t* __restrict__ Vt,
                                                      ushort_t* __restrict__ OpA,
                                                      ushort_t* __restrict__ OpB,
                                                      float* __restrict__ ml) {
    __shared__ ushort_t sK[BKV3 * 256];        // 32768 B, [key][d] rot-swizzled
    __shared__ ushort_t sV[DHEAD * 64];        // 32768 B, [d][key] rot-swizzled
    __shared__ ushort_t sP[4][16 * PPAD];      // 9216 B, per-wave, gq-sequential

    int rem = blockIdx.x, qt = 15, nsp;
    for (;;) {
        nsp = (2 * (qt + 1) + CHCAP - 1) / CHCAP;
        if (rem < nsp) break;
        rem -= nsp;
        qt--;
    }
    const int nch = 2 * (qt + 1);
    const int cbeg = rem * CHCAP;
    const int cend = (cbeg + CHCAP < nch) ? cbeg + CHCAP : nch;

    const int h = blockIdx.y, b = blockIdx.z;
    const int t = threadIdx.x, w = t >> 6, l = t & 63;
    const int lc = l & 15, lq = l >> 4;
    const int bh = b * NHEADS + h;
    const size_t base = (size_t)bh * NS * DHEAD;
    const int q0 = qt * BQ3;

    // per-lane invariant staging offsets (rotation amount is j-invariant)
    const int krb = w * 2 + (l >> 5);                          // K row base (+8 per issue)
    const int kck = ((l & 31) - (krb & 7)) & 31;               // logical chunk
    const size_t koff = (size_t)krb * 256 + kck * 8;           // + (kb + j*8)*256
    const int vrb = w * 8 + (l >> 3);                          // V row base (+32 per issue)
    const int vck = ((l & 7) - (vrb & 7)) & 7;
    const size_t voff = (size_t)vrb * NS + vck * 8;            // + kb + j*32*NS
    ushort_t* dK = &sK[w * 512 + l * 8];                       // + j*2048
    ushort_t* dV = &sV[w * 512 + l * 8];

    // Q fragments: wave w owns rows [q0+w*32, +32), two 16-row groups
    bf16x8 qf[2][8];
#pragma unroll
    for (int gq = 0; gq < 2; gq++) {
        const ushort_t* qrow = Q + base + (size_t)(q0 + w * 32 + gq * 16 + lc) * DHEAD + lq * 8;
#pragma unroll
        for (int dk = 0; dk < 8; dk++) qf[gq][dk] = *(const bf16x8*)(qrow + dk * 32);
    }

    floatx4 accO[2][16];
#pragma unroll
    for (int gq = 0; gq < 2; gq++)
#pragma unroll
        for (int j = 0; j < 16; j++) accO[gq][j] = (floatx4){0.f, 0.f, 0.f, 0.f};
    float lrun[2][4] = {{0.f, 0.f, 0.f, 0.f}, {0.f, 0.f, 0.f, 0.f}};

    for (int kc = cbeg; kc < cend; kc++) {
        const int kb = kc * BKV3;
        __syncthreads();   // prior chunk's LDS reads done (nothing outstanding)
        {
            const ushort_t* ksrc = K + base + (size_t)kb * 256 + koff;
            const ushort_t* vsrc = Vt + base + kb + voff;
#pragma unroll
            for (int j = 0; j < 8; j++)
                gload_lds16(ksrc + j * (8 * 256), dK + j * 2048);
#pragma unroll
            for (int j = 0; j < 8; j++)
                gload_lds16(vsrc + j * (32 * NS), dV + j * 2048);
        }
        QWAITV8;   // K resident; 8 V loads still in flight
        QBAR;

        // S = Q K^T : 8 independent chains; K-frag shared by both q-groups
        floatx4 sfr[2][4];
#pragma unroll
        for (int gq = 0; gq < 2; gq++)
#pragma unroll
            for (int g = 0; g < 4; g++) sfr[gq][g] = (floatx4){0.f, 0.f, 0.f, 0.f};
#pragma unroll
        for (int dk = 0; dk < 8; dk++) {
#pragma unroll
            for (int g = 0; g < 4; g++) {
                int R = g * 16 + lc;
                int phys = (dk * 4 + lq + (R & 7)) & 31;
                bf16x8 bk = *(const bf16x8*)&sK[R * 256 + phys * 8];
                sfr[0][g] = mfma16(qf[0][dk], bk, sfr[0][g]);
                sfr[1][g] = mfma16(qf[1][dk], bk, sfr[1][g]);
            }
        }

        // causal mask only on the two diagonal chunks
        if (kc >= nch - 2) {
#pragma unroll
            for (int gq = 0; gq < 2; gq++)
#pragma unroll
                for (int g = 0; g < 4; g++) {
                    int kg = kb + g * 16 + lc;
                    int qr = q0 + w * 32 + gq * 16 + lq * 4;
#pragma unroll
                    for (int r = 0; r < 4; r++)
                        if (kg > qr + r) sfr[gq][g][r] = -1e30f;
                }
        }

        QWAITV0;   // V resident (latency hidden under QK^T)
        QBAR;

        // gq-sequential: exp -> P(LDS) -> A-frag -> PV
        ushort_t* pw = sP[w];
#pragma unroll
        for (int gq = 0; gq < 2; gq++) {
#pragma unroll
            for (int g = 0; g < 4; g++)
#pragma unroll
                for (int r = 0; r < 4; r++) {
                    float p = __expf(sfr[gq][g][r]);
                    lrun[gq][r] += p;
                    pw[(lq * 4 + r) * PPAD + g * 16 + lc] = f2bf(p);
                }
            bf16x8 ap0 = *(const bf16x8*)&pw[lc * PPAD + lq * 8];
            bf16x8 ap1 = *(const bf16x8*)&pw[lc * PPAD + 32 + lq * 8];
#pragma unroll
            for (int j = 0; j < 16; j++) {
                int D = j * 16 + lc;
                int ph0 = (lq + (D & 7)) & 7;
                int ph1 = (4 + lq + (D & 7)) & 7;
                bf16x8 bv0 = *(const bf16x8*)&sV[D * 64 + ph0 * 8];
                bf16x8 bv1 = *(const bf16x8*)&sV[D * 64 + ph1 * 8];
                accO[gq][j] = mfma16(ap0, bv0, accO[gq][j]);
                accO[gq][j] = mfma16(ap1, bv1, accO[gq][j]);
            }
        }
    }

    // ---- epilogue: unnormalized partial O (bf16) + row sums l ----
    const int pid = bh * NPART_BH + blockIdx.x;
    ushort_t* op = (pid < OPART_SPLIT) ? OpA + (size_t)pid * (128 * 256)
                                       : OpB + (size_t)(pid - OPART_SPLIT) * (128 * 256);
#pragma unroll
    for (int gq = 0; gq < 2; gq++) {
#pragma unroll
        for (int r = 0; r < 4; r++) {
            int row = w * 32 + gq * 16 + lq * 4 + r;
#pragma unroll
            for (int j = 0; j < 16; j++)
                op[row * 256 + j * 16 + lc] = f2bf(accO[gq][j][r]);
            float lv = lrun[gq][r];
#pragma unroll
            for (int off = 1; off < 16; off <<= 1) lv += __shfl_xor(lv, off);
            if (lc == 0) ml[(size_t)pid * 128 + row] = lv;
        }
    }
}

// ---------------- combine partials: fully parallel, vectorized ----------------
__global__ __launch_bounds__(256) void combine_parts2(const ushort_t* __restrict__ OpA,
                                                      const ushort_t* __restrict__ OpB,
                                                      const float* __restrict__ ml,
                                                      ushort_t* __restrict__ O) {
    const int qt = blockIdx.x >> 3, rsub = blockIdx.x & 7;
    const int h = blockIdx.y, b = blockIdx.z;
    const int bh = b * NHEADS + h;
    int bbase = 0;
    for (int q = 15; q > qt; q--) bbase += (2 * (q + 1) + CHCAP - 1) / CHCAP;
    const int nsp = (2 * (qt + 1) + CHCAP - 1) / CHCAP;
    const int pid0 = bh * NPART_BH + bbase;

    const int t = threadIdx.x;
    const int rl = t >> 4;               // 0..15 local row
    const int c0 = (t & 15) * 16;        // col base
    const int row = rsub * 16 + rl;      // row within 128-row q-tile

    float so[16];
#pragma unroll
    for (int k = 0; k < 16; k++) so[k] = 0.f;
    float sl = 0.f;

    for (int i = 0; i < nsp; i++) {
        int pid = pid0 + i;
        const ushort_t* op = (pid < OPART_SPLIT)
                                 ? OpA + (size_t)pid * (128 * 256)
                                 : OpB + (size_t)(pid - OPART_SPLIT) * (128 * 256);
        const ushort_t* p = op + row * 256 + c0;
        ushortx8 a0 = *(const ushortx8*)p;
        ushortx8 a1 = *(const ushortx8*)(p + 8);
#pragma unroll
        for (int k = 0; k < 8; k++) {
            so[k] += bf2f(a0[k]);
            so[8 + k] += bf2f(a1[k]);
        }
        sl += ml[(size_t)pid * 128 + row];
    }

    float inv = 1.f / sl;
    ushortx8 o0, o1;
#pragma unroll
    for (int k = 0; k < 8; k++) {
        o0[k] = f2bf(so[k] * inv);
        o1[k] = f2bf(so[8 + k] * inv);
    }
    int s = qt * BQ3 + row;
    ushort_t* dst = O + ((size_t)(b * NS + s) * NHEADS + h) * DHEAD + c0;
    *(ushortx8*)dst = o0;
    *(ushortx8*)(dst + 8) = o1;
}

// ---------------- launch ----------------
extern "C" void kernel_launch(void* const* d_in, const int* in_sizes, int n_in,
                              void* d_out, int out_size, void* d_ws, size_t ws_size,
                              hipStream_t stream) {
    const float* hidden = (const float*)d_in[0];
    const float* fre = (const float*)d_in[1];
    const float* fim = (const float*)d_in[2];
    // d_in[3] = mask (causal, reproduced analytically)
    const float* Wqkv = (const float*)d_in[4];
    const float* Wo = (const float*)d_in[5];

    char* ws = (char*)d_ws;
    ushort_t* hb    = (ushort_t*)(ws);                 // [0,8M)   dead after gemm_qkv
    ushort_t* wqkvb = (ushort_t*)(ws + 8388608);       // [8,14M)  dead after gemm_qkv
    ushort_t* wob   = (ushort_t*)(ws + 14680064);      // [14,16M) live till gemm2
    ushort_t* qb    = (ushort_t*)(ws + 16777216);      // [16,24M) dead after flash
    ushort_t* kb    = (ushort_t*)(ws + 25165824);      // [24,32M) dead after flash
    ushort_t* vtb   = (ushort_t*)(ws + 33554432);      // [32,40M) dead after flash
    ushort_t* OpA   = (ushort_t*)(ws);                 // [0,14M)  224 partials (over hb+wqkvb)
    ushort_t* OpB   = (ushort_t*)(ws + 41943040);      // [40M,+11.5M) 184 partials, dead after combine
    ushort_t* oattn = (ushort_t*)(ws + 16777216);      // over dead qb, live till gemm2
    float*    ml    = (float*)(ws + 58720256);         // [56M, +209K)

    cast3_kernel<<<(N4_H + N4_WQ + N4_WO) / 256, 256, 0, stream>>>(hidden, Wqkv, Wo, hb);

    gemm_qkv<<<dim3(512), 512, 0, stream>>>(
        hb, wqkvb, fre, fim, qb, kb, vtb);

    flash_attn4<<<dim3(NPART_BH, NHEADS, NB), 256, 0, stream>>>(qb, kb, vtb, OpA, OpB, ml);
    combine_parts2<<<dim3(128, NHEADS, NB), 256, 0, stream>>>(OpA, OpB, ml, oattn);

    gemm_bt_f32s<<<dim3(512), 256, 0, stream>>>(
        oattn, wob, (float*)d_out, 4096, 1024, 1024);
}